// Round 2
// baseline (301.996 us; speedup 1.0000x reference)
//
#include <hip/hip_runtime.h>

// Problem dims
#define B_SZ 32
#define L_SZ 256
#define D_SZ 512
#define F_SZ 2048
#define E_SZ 8
#define P_SZ 64   // B_SZ * TOP_K
#define BK   32   // K-chunk per MFMA step

typedef __attribute__((ext_vector_type(8))) short bf16x8;
typedef __attribute__((ext_vector_type(4))) float f32x4;
typedef __attribute__((ext_vector_type(8))) unsigned short u16x8;

// f32 -> bf16 round-to-nearest-even (finite inputs only)
__device__ __forceinline__ unsigned short f2bf(float f) {
  unsigned int u = __builtin_bit_cast(unsigned int, f);
  u += 0x7fffu + ((u >> 16) & 1u);
  return (unsigned short)(u >> 16);
}

// async global->LDS, 16B per lane; LDS dest is wave-uniform base + lane*16
__device__ __forceinline__ void async16(const void* g, void* l) {
  __builtin_amdgcn_global_load_lds(
      (const __attribute__((address_space(1))) unsigned int*)g,
      (__attribute__((address_space(3))) unsigned int*)l, 16, 0, 0);
}

// exact gelu via A&S 7.1.26 erf (max abs err ~1.5e-7), fast hw exp/rcp
__device__ __forceinline__ float gelu_f(float x) {
  float a = fabsf(x) * 0.70710678118654752f;
  float t = __builtin_amdgcn_rcpf(1.0f + 0.3275911f * a);
  float y = t * (0.254829592f +
            t * (-0.284496736f +
            t * (1.421413741f +
            t * (-1.453152027f +
            t * 1.061405429f))));
  float e = __expf(-a * a);
  float erf_abs = 1.0f - y * e;                 // erf(|x|/sqrt2) in [0,1)
  float erf_v = (x < 0.f) ? -erf_abs : erf_abs;
  return 0.5f * x * (1.0f + erf_v);
}

// ---------------- gates: softmax -> mask -> top2 -> renorm -------------
__global__ void gates_kernel(const float* __restrict__ logits,
                             const int* __restrict__ masks,
                             int* __restrict__ sel_e,
                             float* __restrict__ sel_g) {
  int b = threadIdx.x;
  if (b >= B_SZ) return;
  float lg[E_SZ], p[E_SZ];
  float mx = -1e30f;
  for (int e = 0; e < E_SZ; ++e) { lg[e] = logits[b * E_SZ + e]; mx = fmaxf(mx, lg[e]); }
  float s = 0.f;
  for (int e = 0; e < E_SZ; ++e) { p[e] = expf(lg[e] - mx); s += p[e]; }
  for (int e = 0; e < E_SZ; ++e) p[e] = (masks[b * E_SZ + e] == 1) ? (p[e] / s) : 0.f;
  // top-2, ties -> lower index (strict > replacement), matching lax.top_k
  int i0 = 0, i1 = 1; float v0 = -1.f, v1 = -1.f;
  for (int e = 0; e < E_SZ; ++e) {
    float v = p[e];
    if (v > v0)      { v1 = v0; i1 = i0; v0 = v; i0 = e; }
    else if (v > v1) { v1 = v;  i1 = e; }
  }
  float den = v0 + v1 + 1e-9f;
  sel_e[2 * b]     = i0;  sel_e[2 * b + 1] = i1;
  sel_g[2 * b]     = v0 / den;
  sel_g[2 * b + 1] = v1 / den;
}

// ---------------- f32 -> bf16 (x) -------------------------------------
__global__ void convert_f32_bf16(const float* __restrict__ in,
                                 unsigned short* __restrict__ out, int n4) {
  int i = blockIdx.x * blockDim.x + threadIdx.x;
  if (i >= n4) return;
  float4 v = ((const float4*)in)[i];
  ushort4 o;
  o.x = f2bf(v.x); o.y = f2bf(v.y); o.z = f2bf(v.z); o.w = f2bf(v.w);
  ((ushort4*)out)[i] = o;
}

// ---- transpose+convert, LDS-free: in [z][R][C] f32 -> out [z][C][R] bf16
// thread handles 8 consecutive r at fixed c: 8 lane-coalesced dword loads,
// one 16B ushort8 store. R, C, R/8 all powers of two here.
__global__ void transpose_convert(const float* __restrict__ in,
                                  unsigned short* __restrict__ out,
                                  int R, int C) {
  int t = blockIdx.x * blockDim.x + threadIdx.x;
  int c  = t & (C - 1);
  int r8 = (t / C) & (R / 8 - 1);
  int z  = t / (C * (R / 8));
  const float* ip = in + (size_t)z * R * C + (size_t)(r8 * 8) * C + c;
  u16x8 o;
#pragma unroll
  for (int i = 0; i < 8; ++i) o[i] = f2bf(ip[(size_t)i * C]);
  *(u16x8*)(out + (size_t)z * C * R + (size_t)c * R + r8 * 8) = o;
}

// ------------- bias init: out[b][l][d] = g0*b2[e0][d] + g1*b2[e1][d] ---
__global__ void bias_init(const float* __restrict__ b2,
                          const int* __restrict__ sel_e,
                          const float* __restrict__ sel_g,
                          float* __restrict__ out) {
  int i = blockIdx.x * blockDim.x + threadIdx.x;   // over B*L*D/4
  int d4 = i & (D_SZ / 4 - 1);
  int b  = i >> (7 + 8);                           // /(128*256)
  int e0 = sel_e[2 * b], e1 = sel_e[2 * b + 1];
  float g0 = sel_g[2 * b], g1 = sel_g[2 * b + 1];
  float4 v0 = ((const float4*)(b2 + (size_t)e0 * D_SZ))[d4];
  float4 v1 = ((const float4*)(b2 + (size_t)e1 * D_SZ))[d4];
  float4 r;
  r.x = g0 * v0.x + g1 * v1.x;
  r.y = g0 * v0.y + g1 * v1.y;
  r.z = g0 * v0.z + g1 * v1.z;
  r.w = g0 * v0.w + g1 * v1.w;
  ((float4*)out)[i] = r;
}

// ------------- stage 1: H[p] = gelu(X_b @ W1[e] + b1[e]) ---------------
// Xb [B][L][D] bf16 ; W1t [E][F][D] bf16 (pre-transposed) ; H [P][L][F] bf16
__global__ __launch_bounds__(256, 4) void moe_gemm1(
    const unsigned short* __restrict__ Xb,
    const unsigned short* __restrict__ W1t,
    const float* __restrict__ b1,
    const int* __restrict__ sel_e,
    unsigned short* __restrict__ H) {
  int p = blockIdx.z;
  int b = p >> 1;
  int e = sel_e[p];
  int f0 = blockIdx.x * 128;
  int l0 = blockIdx.y * 128;

  __shared__ __align__(16) unsigned short As[128 * BK];
  __shared__ __align__(16) unsigned short Bs[128 * BK];

  const unsigned short* Abase = Xb  + ((size_t)b * L_SZ + l0) * D_SZ;
  const unsigned short* Bbase = W1t + ((size_t)e * F_SZ + f0) * D_SZ;

  int tid = threadIdx.x;
  int lane = tid & 63;
  int w = tid >> 6, wm = w & 1, wn = w >> 1;
  int lrow = lane & 15, kg = lane >> 4;

  int seg0 = w * 128 + lane;
  int row0 = seg0 >> 2, ks0 = (seg0 & 3) * 8;
  int seg1 = seg0 + 64;
  int row1 = seg1 >> 2, ks1 = (seg1 & 3) * 8;

  f32x4 acc[4][4] = {};

  for (int k0 = 0; k0 < D_SZ; k0 += BK) {
    async16(Abase + (size_t)row0 * D_SZ + k0 + ks0, &As[seg0 * 8]);
    async16(Abase + (size_t)row1 * D_SZ + k0 + ks1, &As[seg1 * 8]);
    async16(Bbase + (size_t)row0 * D_SZ + k0 + ks0, &Bs[seg0 * 8]);
    async16(Bbase + (size_t)row1 * D_SZ + k0 + ks1, &Bs[seg1 * 8]);
    __syncthreads();
    bf16x8 af[4], bfr[4];
#pragma unroll
    for (int i = 0; i < 4; ++i)
      af[i] = *(const bf16x8*)&As[(wm * 64 + i * 16 + lrow) * BK + kg * 8];
#pragma unroll
    for (int j = 0; j < 4; ++j)
      bfr[j] = *(const bf16x8*)&Bs[(wn * 64 + j * 16 + lrow) * BK + kg * 8];
#pragma unroll
    for (int i = 0; i < 4; ++i)
#pragma unroll
      for (int j = 0; j < 4; ++j)
        acc[i][j] = __builtin_amdgcn_mfma_f32_16x16x32_bf16(af[i], bfr[j], acc[i][j], 0, 0, 0);
    __syncthreads();
  }

  // epilogue: + b1, exact gelu (fast poly), bf16 store to H
  unsigned short* Hp = H + ((size_t)p * L_SZ + l0) * F_SZ + f0;
  float b1v[4];
#pragma unroll
  for (int j = 0; j < 4; ++j)
    b1v[j] = b1[e * F_SZ + f0 + wn * 64 + j * 16 + lrow];
#pragma unroll
  for (int i = 0; i < 4; ++i) {
    int rbase = wm * 64 + i * 16 + kg * 4;
#pragma unroll
    for (int j = 0; j < 4; ++j) {
      int c = wn * 64 + j * 16 + lrow;
#pragma unroll
      for (int r = 0; r < 4; ++r) {
        float v = gelu_f(acc[i][j][r] + b1v[j]);
        Hp[(size_t)(rbase + r) * F_SZ + c] = f2bf(v);
      }
    }
  }
}

// ------------- stage 2 (split expert-slot + split-K, atomic combine) ---
// H [P][L][F] bf16 ; W2t [E][D][F] bf16 ; Out [B][L][D] f32 (pre-biased)
// blockIdx.z = p*2 + kh : expert-slot p (0..63), K-half kh (0..1)
__global__ __launch_bounds__(256, 4) void moe_gemm2(
    const unsigned short* __restrict__ H,
    const unsigned short* __restrict__ W2t,
    const int* __restrict__ sel_e,
    const float* __restrict__ sel_g,
    float* __restrict__ Out) {
  int zz = blockIdx.z;
  int p = zz >> 1, kh = zz & 1;
  int b = p >> 1;
  int e = sel_e[p];
  float g = sel_g[p];
  int d0 = blockIdx.x * 128;
  int l0 = blockIdx.y * 128;

  __shared__ __align__(16) unsigned short As[128 * BK];
  __shared__ __align__(16) unsigned short Bs[128 * BK];

  int tid = threadIdx.x;
  int lane = tid & 63;
  int w = tid >> 6, wm = w & 1, wn = w >> 1;
  int lrow = lane & 15, kg = lane >> 4;
  int seg0 = w * 128 + lane;
  int row0 = seg0 >> 2, ks0 = (seg0 & 3) * 8;
  int seg1 = seg0 + 64;
  int row1 = seg1 >> 2, ks1 = (seg1 & 3) * 8;

  const unsigned short* Abase = H   + ((size_t)p * L_SZ + l0) * F_SZ + kh * (F_SZ / 2);
  const unsigned short* Bbase = W2t + ((size_t)e * D_SZ + d0) * F_SZ + kh * (F_SZ / 2);

  f32x4 acc[4][4] = {};
  for (int k0 = 0; k0 < F_SZ / 2; k0 += BK) {
    async16(Abase + (size_t)row0 * F_SZ + k0 + ks0, &As[seg0 * 8]);
    async16(Abase + (size_t)row1 * F_SZ + k0 + ks1, &As[seg1 * 8]);
    async16(Bbase + (size_t)row0 * F_SZ + k0 + ks0, &Bs[seg0 * 8]);
    async16(Bbase + (size_t)row1 * F_SZ + k0 + ks1, &Bs[seg1 * 8]);
    __syncthreads();
    bf16x8 af[4], bfr[4];
#pragma unroll
    for (int i = 0; i < 4; ++i)
      af[i] = *(const bf16x8*)&As[(wm * 64 + i * 16 + lrow) * BK + kg * 8];
#pragma unroll
    for (int j = 0; j < 4; ++j)
      bfr[j] = *(const bf16x8*)&Bs[(wn * 64 + j * 16 + lrow) * BK + kg * 8];
#pragma unroll
    for (int i = 0; i < 4; ++i)
#pragma unroll
      for (int j = 0; j < 4; ++j)
        acc[i][j] = __builtin_amdgcn_mfma_f32_16x16x32_bf16(af[i], bfr[j], acc[i][j], 0, 0, 0);
    __syncthreads();
  }

  // epilogue: gate-scaled atomic accumulate into pre-biased Out
  float* Op = Out + ((size_t)b * L_SZ + l0) * D_SZ + d0;
#pragma unroll
  for (int i = 0; i < 4; ++i) {
    int rbase = wm * 64 + i * 16 + kg * 4;
#pragma unroll
    for (int j = 0; j < 4; ++j) {
      int c = wn * 64 + j * 16 + lrow;
#pragma unroll
      for (int r = 0; r < 4; ++r)
        unsafeAtomicAdd(&Op[(size_t)(rbase + r) * D_SZ + c], g * acc[i][j][r]);
    }
  }
}

extern "C" void kernel_launch(void* const* d_in, const int* in_sizes, int n_in,
                              void* d_out, int out_size, void* d_ws, size_t ws_size,
                              hipStream_t stream) {
  const float* x      = (const float*)d_in[0];
  const float* logits = (const float*)d_in[1];
  const int*   masks  = (const int*)d_in[2];
  const float* W1     = (const float*)d_in[3];
  const float* b1     = (const float*)d_in[4];
  const float* W2     = (const float*)d_in[5];
  const float* b2     = (const float*)d_in[6];
  float* out = (float*)d_out;

  // workspace layout (~105 MB):
  //   sel_e (256B) | sel_g (256B) | pad | xb 8MB | w1t 16MB | w2t 16MB | H 64MB
  char* ws = (char*)d_ws;
  int*   sel_e = (int*)ws;
  float* sel_g = (float*)(ws + 256);
  unsigned short* xb  = (unsigned short*)(ws + 1024);
  unsigned short* w1t = xb  + (size_t)B_SZ * L_SZ * D_SZ;
  unsigned short* w2t = w1t + (size_t)E_SZ * F_SZ * D_SZ;
  unsigned short* Hbuf = w2t + (size_t)E_SZ * D_SZ * F_SZ;

  gates_kernel<<<1, 64, 0, stream>>>(logits, masks, sel_e, sel_g);

  int n4 = (B_SZ * L_SZ * D_SZ) / 4;
  convert_f32_bf16<<<n4 / 256, 256, 0, stream>>>(x, xb, n4);

  // W1 [E][D][F] -> w1t [E][F][D] : R=D, C=F
  transpose_convert<<<(E_SZ * F_SZ * (D_SZ / 8)) / 256, 256, 0, stream>>>(W1, w1t, D_SZ, F_SZ);
  // W2 [E][F][D] -> w2t [E][D][F] : R=F, C=D
  transpose_convert<<<(E_SZ * D_SZ * (F_SZ / 8)) / 256, 256, 0, stream>>>(W2, w2t, F_SZ, D_SZ);

  // out = gate-weighted b2 (also clears the 0xAA poison)
  bias_init<<<(B_SZ * L_SZ * D_SZ / 4) / 256, 256, 0, stream>>>(b2, sel_e, sel_g, out);

  moe_gemm1<<<dim3(F_SZ / 128, L_SZ / 128, P_SZ), 256, 0, stream>>>(xb, w1t, b1, sel_e, Hbuf);
  moe_gemm2<<<dim3(D_SZ / 128, L_SZ / 128, P_SZ * 2), 256, 0, stream>>>(Hbuf, w2t, sel_e, sel_g, out);
}

// Round 3
// 244.454 us; speedup vs baseline: 1.2354x; 1.2354x over previous
//
#include <hip/hip_runtime.h>

// Problem dims
#define B_SZ 32
#define L_SZ 256
#define D_SZ 512
#define F_SZ 2048
#define E_SZ 8
#define P_SZ 64   // B_SZ * TOP_K
#define BK   32   // K-chunk per MFMA step

typedef __attribute__((ext_vector_type(8))) short bf16x8;
typedef __attribute__((ext_vector_type(4))) float f32x4;

// f32 -> bf16 round-to-nearest-even (finite inputs only)
__device__ __forceinline__ unsigned short f2bf(float f) {
  unsigned int u = __builtin_bit_cast(unsigned int, f);
  u += 0x7fffu + ((u >> 16) & 1u);
  return (unsigned short)(u >> 16);
}

// async global->LDS, 16B per lane; LDS dest is wave-uniform base + lane*16
__device__ __forceinline__ void async16(const void* g, void* l) {
  __builtin_amdgcn_global_load_lds(
      (const __attribute__((address_space(1))) unsigned int*)g,
      (__attribute__((address_space(3))) unsigned int*)l, 16, 0, 0);
}

// exact gelu via A&S 7.1.26 erf (max abs err ~1.5e-7), fast hw exp/rcp
__device__ __forceinline__ float gelu_f(float x) {
  float a = fabsf(x) * 0.70710678118654752f;
  float t = __builtin_amdgcn_rcpf(1.0f + 0.3275911f * a);
  float y = t * (0.254829592f +
            t * (-0.284496736f +
            t * (1.421413741f +
            t * (-1.453152027f +
            t * 1.061405429f))));
  float e = __expf(-a * a);
  float erf_abs = 1.0f - y * e;
  float erf_v = (x < 0.f) ? -erf_abs : erf_abs;
  return 0.5f * x * (1.0f + erf_v);
}

// ------------- fused prep: gates | x->bf16 | W1^T->bf16 | W2^T->bf16 ----
// block 0:                      gates
// blocks [1, 1+4096):           convert x (float4 -> ushort4)
// blocks [4097, 4097+2048):     transpose W1 [E][D][F] -> w1t [E][F][D]
// blocks [6145, 6145+2048):     transpose W2 [E][F][D] -> w2t [E][D][F]
#define PREP_CONV_BLKS 4096
#define PREP_TR_BLKS   2048
#define PREP_TOTAL     (1 + PREP_CONV_BLKS + 2 * PREP_TR_BLKS)

__global__ __launch_bounds__(256) void prep_kernel(
    const float* __restrict__ logits, const int* __restrict__ masks,
    const float* __restrict__ x,
    const float* __restrict__ W1, const float* __restrict__ W2,
    int* __restrict__ sel_e, float* __restrict__ sel_g,
    unsigned short* __restrict__ xb,
    unsigned short* __restrict__ w1t, unsigned short* __restrict__ w2t) {
  __shared__ float tile[64][65];
  int blk = blockIdx.x;
  int tid = threadIdx.x;

  if (blk == 0) {
    int b = tid;
    if (b >= B_SZ) return;
    float lg[E_SZ], p[E_SZ];
    float mx = -1e30f;
    for (int e = 0; e < E_SZ; ++e) { lg[e] = logits[b * E_SZ + e]; mx = fmaxf(mx, lg[e]); }
    float s = 0.f;
    for (int e = 0; e < E_SZ; ++e) { p[e] = expf(lg[e] - mx); s += p[e]; }
    for (int e = 0; e < E_SZ; ++e) p[e] = (masks[b * E_SZ + e] == 1) ? (p[e] / s) : 0.f;
    int i0 = 0, i1 = 1; float v0 = -1.f, v1 = -1.f;
    for (int e = 0; e < E_SZ; ++e) {
      float v = p[e];
      if (v > v0)      { v1 = v0; i1 = i0; v0 = v; i0 = e; }
      else if (v > v1) { v1 = v;  i1 = e; }
    }
    float den = v0 + v1 + 1e-9f;
    sel_e[2 * b] = i0;  sel_e[2 * b + 1] = i1;
    sel_g[2 * b] = v0 / den;
    sel_g[2 * b + 1] = v1 / den;
    return;
  }
  blk -= 1;

  if (blk < PREP_CONV_BLKS) {
    int i = blk * 256 + tid;
    float4 v = ((const float4*)x)[i];
    ushort4 o;
    o.x = f2bf(v.x); o.y = f2bf(v.y); o.z = f2bf(v.z); o.w = f2bf(v.w);
    ((ushort4*)xb)[i] = o;
    return;
  }
  blk -= PREP_CONV_BLKS;

  // LDS tile transpose+convert: in [z][R][C] f32 -> out [z][C][R] bf16
  const float* in; unsigned short* out; int R, C, ls;
  if (blk < PREP_TR_BLKS) { in = W1; out = w1t; R = D_SZ; C = F_SZ; ls = 5; }
  else { blk -= PREP_TR_BLKS; in = W2; out = w2t; R = F_SZ; C = D_SZ; ls = 3; }
  int z = blk >> 8;            // 256 tiles per expert
  int rem = blk & 255;
  int tr = rem >> ls, tc = rem & ((1 << ls) - 1);
  int r0 = tr * 64, c0 = tc * 64;
  const float* ip = in + (size_t)z * R * C;
  unsigned short* op = out + (size_t)z * C * R;
  int tx = tid & 63, ty = tid >> 6;
#pragma unroll
  for (int i = 0; i < 16; ++i) {
    int r = i * 4 + ty;
    tile[r][tx] = ip[(size_t)(r0 + r) * C + c0 + tx];   // coalesced 256B
  }
  __syncthreads();
#pragma unroll
  for (int uu = 0; uu < 4; ++uu) {
    int u = uu * 256 + tid;
    int cc = u >> 4, q = u & 15;
    ushort4 o;
    o.x = f2bf(tile[q * 4 + 0][cc]);
    o.y = f2bf(tile[q * 4 + 1][cc]);
    o.z = f2bf(tile[q * 4 + 2][cc]);
    o.w = f2bf(tile[q * 4 + 3][cc]);
    *(ushort4*)(op + (size_t)(c0 + cc) * R + r0 + q * 4) = o;  // 128B/16-lane seg
  }
}

// ------------- stage 1: H[p] = gelu(X_b @ W1[e] + b1[e]) ---------------
// Xb [B][L][D] bf16 ; W1t [E][F][D] bf16 ; H [P][L][F] bf16
__global__ __launch_bounds__(256, 4) void moe_gemm1(
    const unsigned short* __restrict__ Xb,
    const unsigned short* __restrict__ W1t,
    const float* __restrict__ b1,
    const int* __restrict__ sel_e,
    unsigned short* __restrict__ H) {
  int p = blockIdx.z;
  int b = p >> 1;
  int e = sel_e[p];
  int f0 = blockIdx.x * 128;
  int l0 = blockIdx.y * 128;

  __shared__ __align__(16) unsigned short As[128 * BK];
  __shared__ __align__(16) unsigned short Bs[128 * BK];

  const unsigned short* Abase = Xb  + ((size_t)b * L_SZ + l0) * D_SZ;
  const unsigned short* Bbase = W1t + ((size_t)e * F_SZ + f0) * D_SZ;

  int tid = threadIdx.x;
  int lane = tid & 63;
  int w = tid >> 6, wm = w & 1, wn = w >> 1;
  int lrow = lane & 15, kg = lane >> 4;

  int seg0 = w * 128 + lane;
  int row0 = seg0 >> 2, ks0 = (seg0 & 3) * 8;
  int seg1 = seg0 + 64;
  int row1 = seg1 >> 2, ks1 = (seg1 & 3) * 8;

  f32x4 acc[4][4] = {};

  for (int k0 = 0; k0 < D_SZ; k0 += BK) {
    async16(Abase + (size_t)row0 * D_SZ + k0 + ks0, &As[seg0 * 8]);
    async16(Abase + (size_t)row1 * D_SZ + k0 + ks1, &As[seg1 * 8]);
    async16(Bbase + (size_t)row0 * D_SZ + k0 + ks0, &Bs[seg0 * 8]);
    async16(Bbase + (size_t)row1 * D_SZ + k0 + ks1, &Bs[seg1 * 8]);
    __syncthreads();
    bf16x8 af[4], bfr[4];
#pragma unroll
    for (int i = 0; i < 4; ++i)
      af[i] = *(const bf16x8*)&As[(wm * 64 + i * 16 + lrow) * BK + kg * 8];
#pragma unroll
    for (int j = 0; j < 4; ++j)
      bfr[j] = *(const bf16x8*)&Bs[(wn * 64 + j * 16 + lrow) * BK + kg * 8];
#pragma unroll
    for (int i = 0; i < 4; ++i)
#pragma unroll
      for (int j = 0; j < 4; ++j)
        acc[i][j] = __builtin_amdgcn_mfma_f32_16x16x32_bf16(af[i], bfr[j], acc[i][j], 0, 0, 0);
    __syncthreads();
  }

  unsigned short* Hp = H + ((size_t)p * L_SZ + l0) * F_SZ + f0;
  float b1v[4];
#pragma unroll
  for (int j = 0; j < 4; ++j)
    b1v[j] = b1[e * F_SZ + f0 + wn * 64 + j * 16 + lrow];
#pragma unroll
  for (int i = 0; i < 4; ++i) {
    int rbase = wm * 64 + i * 16 + kg * 4;
#pragma unroll
    for (int j = 0; j < 4; ++j) {
      int c = wn * 64 + j * 16 + lrow;
#pragma unroll
      for (int r = 0; r < 4; ++r) {
        float v = gelu_f(acc[i][j][r] + b1v[j]);
        Hp[(size_t)(rbase + r) * F_SZ + c] = f2bf(v);
      }
    }
  }
}

// ------------- stage 2 (slot-split, full K, no atomics) ----------------
// H [P][L][F] bf16 ; W2t [E][D][F] bf16
// even slot p -> part[b][l][d] = g0*acc ; odd slot p -> Out[b][l][d] = g1*acc
// 1-D grid of 512, swizzled so the 4 d-tiles sharing an H-tile land on the
// same XCD (lin%8 invariant across d) and are temporally adjacent.
__global__ __launch_bounds__(256, 4) void moe_gemm2(
    const unsigned short* __restrict__ H,
    const unsigned short* __restrict__ W2t,
    const int* __restrict__ sel_e,
    const float* __restrict__ sel_g,
    float* __restrict__ part,
    float* __restrict__ Out) {
  int lin = blockIdx.x;
  int q   = lin & 7;
  int d   = (lin >> 3) & 3;
  int g8  = lin >> 5;
  int gg  = g8 * 8 + q;        // (p, l-tile) pair, 0..127
  int p   = gg >> 1;
  int l0  = (gg & 1) * 128;
  int d0  = d * 128;
  int b   = p >> 1;
  int e   = sel_e[p];
  float g = sel_g[p];
  float* dst = (p & 1) ? Out : part;

  __shared__ __align__(16) unsigned short As[128 * BK];
  __shared__ __align__(16) unsigned short Bs[128 * BK];

  int tid = threadIdx.x;
  int lane = tid & 63;
  int w = tid >> 6, wm = w & 1, wn = w >> 1;
  int lrow = lane & 15, kg = lane >> 4;
  int seg0 = w * 128 + lane;
  int row0 = seg0 >> 2, ks0 = (seg0 & 3) * 8;
  int seg1 = seg0 + 64;
  int row1 = seg1 >> 2, ks1 = (seg1 & 3) * 8;

  const unsigned short* Abase = H   + ((size_t)p * L_SZ + l0) * F_SZ;
  const unsigned short* Bbase = W2t + ((size_t)e * D_SZ + d0) * F_SZ;

  f32x4 acc[4][4] = {};
  for (int k0 = 0; k0 < F_SZ; k0 += BK) {
    async16(Abase + (size_t)row0 * F_SZ + k0 + ks0, &As[seg0 * 8]);
    async16(Abase + (size_t)row1 * F_SZ + k0 + ks1, &As[seg1 * 8]);
    async16(Bbase + (size_t)row0 * F_SZ + k0 + ks0, &Bs[seg0 * 8]);
    async16(Bbase + (size_t)row1 * F_SZ + k0 + ks1, &Bs[seg1 * 8]);
    __syncthreads();
    bf16x8 af[4], bfr[4];
#pragma unroll
    for (int i = 0; i < 4; ++i)
      af[i] = *(const bf16x8*)&As[(wm * 64 + i * 16 + lrow) * BK + kg * 8];
#pragma unroll
    for (int j = 0; j < 4; ++j)
      bfr[j] = *(const bf16x8*)&Bs[(wn * 64 + j * 16 + lrow) * BK + kg * 8];
#pragma unroll
    for (int i = 0; i < 4; ++i)
#pragma unroll
      for (int j = 0; j < 4; ++j)
        acc[i][j] = __builtin_amdgcn_mfma_f32_16x16x32_bf16(af[i], bfr[j], acc[i][j], 0, 0, 0);
    __syncthreads();
  }

  float* Op = dst + ((size_t)b * L_SZ + l0) * D_SZ + d0;
#pragma unroll
  for (int i = 0; i < 4; ++i) {
    int rbase = wm * 64 + i * 16 + kg * 4;
#pragma unroll
    for (int j = 0; j < 4; ++j) {
      int c = wn * 64 + j * 16 + lrow;
#pragma unroll
      for (int r = 0; r < 4; ++r)
        Op[(size_t)(rbase + r) * D_SZ + c] = g * acc[i][j][r];
    }
  }
}

// ------------- combine: Out += part + g0*b2[e0] + g1*b2[e1] ------------
__global__ __launch_bounds__(256) void combine_kernel(
    const float* __restrict__ part, const float* __restrict__ b2,
    const int* __restrict__ sel_e, const float* __restrict__ sel_g,
    float* __restrict__ Out) {
  int i = blockIdx.x * 256 + threadIdx.x;     // over B*L*D/4
  int d4 = i & (D_SZ / 4 - 1);
  int b  = i >> 15;                           // /(L*D/4) = /32768
  int e0 = sel_e[2 * b], e1 = sel_e[2 * b + 1];
  float g0 = sel_g[2 * b], g1 = sel_g[2 * b + 1];
  float4 pv = ((const float4*)part)[i];
  float4 o  = ((float4*)Out)[i];
  float4 v0 = ((const float4*)(b2 + (size_t)e0 * D_SZ))[d4];
  float4 v1 = ((const float4*)(b2 + (size_t)e1 * D_SZ))[d4];
  o.x += pv.x + g0 * v0.x + g1 * v1.x;
  o.y += pv.y + g0 * v0.y + g1 * v1.y;
  o.z += pv.z + g0 * v0.z + g1 * v1.z;
  o.w += pv.w + g0 * v0.w + g1 * v1.w;
  ((float4*)Out)[i] = o;
}

extern "C" void kernel_launch(void* const* d_in, const int* in_sizes, int n_in,
                              void* d_out, int out_size, void* d_ws, size_t ws_size,
                              hipStream_t stream) {
  const float* x      = (const float*)d_in[0];
  const float* logits = (const float*)d_in[1];
  const int*   masks  = (const int*)d_in[2];
  const float* W1     = (const float*)d_in[3];
  const float* b1     = (const float*)d_in[4];
  const float* W2     = (const float*)d_in[5];
  const float* b2     = (const float*)d_in[6];
  float* out = (float*)d_out;

  // workspace layout (104 MB):
  //   sel (1K) | xb 8MB | w1t 16MB | w2t 16MB | H 64MB
  // part (16MB f32) aliases [xb .. first half of w1t] — both dead after gemm1.
  char* ws = (char*)d_ws;
  int*   sel_e = (int*)ws;
  float* sel_g = (float*)(ws + 256);
  unsigned short* xb  = (unsigned short*)(ws + 1024);
  unsigned short* w1t = xb  + (size_t)B_SZ * L_SZ * D_SZ;
  unsigned short* w2t = w1t + (size_t)E_SZ * F_SZ * D_SZ;
  unsigned short* Hbuf = w2t + (size_t)E_SZ * D_SZ * F_SZ;
  float* part = (float*)(ws + 1024);

  prep_kernel<<<PREP_TOTAL, 256, 0, stream>>>(logits, masks, x, W1, W2,
                                              sel_e, sel_g, xb, w1t, w2t);
  moe_gemm1<<<dim3(F_SZ / 128, L_SZ / 128, P_SZ), 256, 0, stream>>>(
      xb, w1t, b1, sel_e, Hbuf);
  moe_gemm2<<<512, 256, 0, stream>>>(Hbuf, w2t, sel_e, sel_g, part, out);
  combine_kernel<<<(B_SZ * L_SZ * D_SZ / 4) / 256, 256, 0, stream>>>(
      part, b2, sel_e, sel_g, out);
}